// Round 16
// baseline (119.761 us; speedup 1.0000x reference)
//
#include <hip/hip_runtime.h>
#include <hip/hip_bf16.h>
#include <stdint.h>
#include <stddef.h>

typedef __attribute__((ext_vector_type(8))) short short8;
typedef __attribute__((ext_vector_type(4))) float f32x4;
typedef __attribute__((ext_vector_type(16))) float f32x16;
typedef __attribute__((ext_vector_type(4))) unsigned int uint4v;

#define MFMA16(a, b, c) __builtin_amdgcn_mfma_f32_16x16x32_bf16((a), (b), (c), 0, 0, 0)
#define MFMA32(a, b, c) __builtin_amdgcn_mfma_f32_32x32x16_bf16((a), (b), (c), 0, 0, 0)

__device__ __forceinline__ unsigned short f2bf(float f) {
  unsigned int u = __builtin_bit_cast(unsigned int, f);
  u += 0x7fffu + ((u >> 16) & 1u);
  return (unsigned short)(u >> 16);
}

// validated integer RNE pack — cold paths
__device__ __forceinline__ unsigned int pk2(float lo, float hi) {
  return (unsigned int)f2bf(lo) | ((unsigned int)f2bf(hi) << 16);
}

// hot-path pack: official intrinsic -> compiler-emitted v_cvt_pk_bf16_f32
__device__ __forceinline__ unsigned int pkc(float lo, float hi) {
  __hip_bfloat162 h = __float22bfloat162_rn(make_float2(lo, hi));
  unsigned int u;
  __builtin_memcpy(&u, &h, 4);
  return u;
}

__device__ __forceinline__ short8 mk8(const unsigned short* p) {
  return *(const short8*)p;
}

__device__ __forceinline__ float redsum32(float v) {
  return v + __shfl_xor(v, 32);
}

__device__ __forceinline__ f32x16 zero16() {
  f32x16 v;
#pragma unroll
  for (int i = 0; i < 16; ++i) v[i] = 0.f;
  return v;
}

// swizzled offset into a [rows][40]-half LDS tile holding 32 data cols.
__device__ __forceinline__ int swz40(int row, int c) {
  return row * 40 + ((((c >> 3) ^ (row >> 3)) & 3) << 3) + (c & 7);
}

// ---------------- kernel 0: cast weights to bf16 ----------------
__global__ __launch_bounds__(256) void k_prep(const float* __restrict__ wq,
                                              const float* __restrict__ wo,
                                              unsigned short* __restrict__ wq_bf,
                                              unsigned short* __restrict__ wo_bf) {
  int i = blockIdx.x * 256 + threadIdx.x;
  if (i < 98304) wq_bf[i] = f2bf(wq[i]);
  if (i < 32768) wo_bf[i] = f2bf(wo[i]);
}

// ---------------- kernel 1: fused RMSNorm + QKV GEMM (r15, unchanged) ----------------
__global__ __launch_bounds__(256) void k_qkv(const float* __restrict__ x,
                                             const float* __restrict__ g,
                                             const unsigned short* __restrict__ wq_bf,
                                             unsigned short* __restrict__ qbuf,
                                             unsigned short* __restrict__ kbuf,
                                             unsigned short* __restrict__ vbuf) {
  int bid = blockIdx.x;            // 768 = 4b * 6ot * 32pt
  int b = bid / 192;
  int rem = bid % 192;
  int ot = rem / 32;
  int pt = rem % 32;
  int o0 = ot * 64, p0 = pt * 128;

  __shared__ unsigned short xnT[2][128 * 40];
  __shared__ float sqv[8][128];
  __shared__ float rl[128];

  int t = threadIdx.x;
  int lane = t & 63, w = t >> 6;
  int lr = lane & 15, lg = lane >> 4;
  int pq = t & 31;                 // p-quad: p = p0 + pq*4 + k
  int cp = t >> 5;                 // c-pair group 0..7

  const float* xb = x + (size_t)b * 256 * 4096;
  const unsigned short* wqrow = wq_bf + (size_t)(o0 + w * 16 + lr) * 256;

  f32x4 acc[8];
  f32x4 z = {0.f, 0.f, 0.f, 0.f};
#pragma unroll
  for (int i = 0; i < 8; ++i) acc[i] = z;
  f32x4 sacc = z;

#define STAGE_CHUNK(buf, c0)                                                   \
  {                                                                            \
    _Pragma("unroll")                                                          \
    for (int s = 0; s < 2; ++s) {                                              \
      int cb = (c0) + s * 16 + cp * 2;                                         \
      f32x4 xa = *(const f32x4*)&xb[(size_t)cb * 4096 + p0 + pq * 4];          \
      f32x4 xc = *(const f32x4*)&xb[(size_t)(cb + 1) * 4096 + p0 + pq * 4];    \
      float ga = g[cb], gc = g[cb + 1];                                        \
      int cloc = s * 16 + cp * 2;                                              \
      _Pragma("unroll")                                                        \
      for (int k = 0; k < 4; ++k) {                                            \
        sacc[k] += xa[k] * xa[k] + xc[k] * xc[k];                              \
        *(unsigned int*)&xnT[buf][swz40(pq * 4 + k, cloc)] =                   \
            pkc(xa[k] * ga, xc[k] * gc);                                       \
      }                                                                        \
    }                                                                          \
  }

  STAGE_CHUNK(0, 0)
  __syncthreads();

  for (int cc = 0; cc < 8; ++cc) {
    int cur = cc & 1;
    if (cc < 7) STAGE_CHUNK(cur ^ 1, (cc + 1) * 32)
    short8 af = mk8(wqrow + cc * 32 + lg * 8);
#pragma unroll
    for (int pt16 = 0; pt16 < 8; ++pt16) {
      short8 bf = mk8(&xnT[cur][swz40(pt16 * 16 + lr, lg * 8)]);
      acc[pt16] = MFMA16(af, bf, acc[pt16]);
    }
    __syncthreads();
  }
#undef STAGE_CHUNK

#pragma unroll
  for (int k = 0; k < 4; ++k) sqv[cp][pq * 4 + k] = sacc[k];
  __syncthreads();
  if (t < 128) {
    float tot = 0.f;
#pragma unroll
    for (int r = 0; r < 8; ++r) tot += sqv[r][t];
    rl[t] = rsqrtf(tot * (1.0f / 256.0f) + 1e-12f);
  }
  __syncthreads();

  const float cexp = 0.25505654427102996f;   // 32^-0.5 * log2(e), folded into K
  int obase = o0 + w * 16 + lg * 4;          // multiple of 4
  if (obase < 128) {
    int h = obase >> 5, d0 = obase & 31;
    unsigned short* dst = qbuf + ((size_t)(b * 4 + h) * 4096) * 32;
#pragma unroll
    for (int pt16 = 0; pt16 < 8; ++pt16) {
      int p = p0 + pt16 * 16 + lr;
      float rr = rl[pt16 * 16 + lr];
      unsigned int u0 = pk2(acc[pt16][0] * rr, acc[pt16][1] * rr);
      unsigned int u1 = pk2(acc[pt16][2] * rr, acc[pt16][3] * rr);
      uint2 uu = {u0, u1};
      *(uint2*)(dst + (size_t)p * 32 + d0) = uu;
    }
  } else if (obase < 256) {
    int oh = obase - 128;
    int h = oh >> 5, d0 = oh & 31;
    int frag = d0 >> 4, hi = (d0 >> 3) & 1, i0 = d0 & 7;
    unsigned short* dst = kbuf + (size_t)(b * 4 + h) * 131072
                         + frag * 512 + hi * 256 + i0;
#pragma unroll
    for (int pt16 = 0; pt16 < 8; ++pt16) {
      int jj = p0 + pt16 * 16 + lr;
      float rr = rl[pt16 * 16 + lr] * cexp;
      int jtile = jj >> 5, j31 = jj & 31;
      uint2 uu = {pk2(acc[pt16][0] * rr, acc[pt16][1] * rr),
                  pk2(acc[pt16][2] * rr, acc[pt16][3] * rr)};
      *(uint2*)(dst + (size_t)jtile * 1024 + j31 * 8) = uu;
    }
  } else {
    int oh = obase - 256;
    int h = oh >> 5, d0 = oh & 31;
    unsigned short* dst = vbuf + (size_t)(b * 4 + h) * 131072;
    int sl = (lr & 3) | ((lr & 4) << 1) | ((lr & 8) >> 1);
#pragma unroll
    for (int pt16 = 0; pt16 < 8; ++pt16) {
      int jj = p0 + pt16 * 16 + sl;
      float rr = rl[pt16 * 16 + lr];
      int jtile = jj >> 5, j5 = jj & 31;
      int frag = j5 >> 4, hi = (j5 >> 3) & 1, i = j5 & 7;
      size_t base = (size_t)jtile * 1024 + frag * 512 + hi * 256 + i;
#pragma unroll
      for (int r = 0; r < 4; ++r)
        dst[base + (d0 + r) * 8] = f2bf(acc[pt16][r] * rr);
    }
  }
}

// ---------------- kernel 2: flash attention, 2 q-subgroups per wave ----------------
// grid 1024 = 16 bh x 64 q-groups of 64 rows; 4 waves = 4 j-quarters.
// Each wave reuses every K/V fragment for TWO 32-row q-subgroups -> L1 bytes/FLOP
// halved (was ~86% of TCP port). Shift-free softmax (K pre-scaled by cexp).
__device__ __forceinline__ void attn_sub(short8 kf0, short8 kf1, short8 vf0, short8 vf1,
                                         short8 qf0, short8 qf1,
                                         const f32x16& z16, float& lsum, f32x16& oacc) {
  f32x16 s = MFMA32(kf0, qf0, z16);
  s = MFMA32(kf1, qf1, s);

  float p[16];
#pragma unroll
  for (int i = 0; i < 16; ++i) p[i] = __builtin_amdgcn_exp2f(s[i]);

  float s0 = ((p[0] + p[1]) + (p[2] + p[3])) + ((p[4] + p[5]) + (p[6] + p[7]));
  float s1 = ((p[8] + p[9]) + (p[10] + p[11])) + ((p[12] + p[13]) + (p[14] + p[15]));
  lsum += s0 + s1;

  uint4v u0 = {pkc(p[0], p[1]), pkc(p[2], p[3]), pkc(p[4], p[5]), pkc(p[6], p[7])};
  uint4v u1 = {pkc(p[8], p[9]), pkc(p[10], p[11]), pkc(p[12], p[13]), pkc(p[14], p[15])};
  short8 pf0 = __builtin_bit_cast(short8, u0);
  short8 pf1 = __builtin_bit_cast(short8, u1);

  oacc = MFMA32(vf0, pf0, oacc);
  oacc = MFMA32(vf1, pf1, oacc);
}

__global__ __launch_bounds__(256, 4) void k_attn(const unsigned short* __restrict__ qbuf,
                                                 const unsigned short* __restrict__ kbuf,
                                                 const unsigned short* __restrict__ vbuf,
                                                 unsigned short* __restrict__ attno) {
  __shared__ float Ol[3][2][16][64];   // partner O partials (jq 1..3, 2 subgroups)
  __shared__ float Ll[3][2][64];       // partner lsum

  int bid = blockIdx.x;
  int wid = ((bid & 7) << 7) | (bid >> 3);   // XCD-contiguous (1024 % 8 == 0)
  int qg = wid & 63, bh = wid >> 6;
  int t = threadIdx.x, lane = t & 63, jq = t >> 6;
  int l31 = lane & 31, hi = lane >> 5;

  const unsigned short* qgp = qbuf + (size_t)bh * 4096 * 32;
  const unsigned short* kt = kbuf + (size_t)bh * 131072;
  const unsigned short* vt = vbuf + (size_t)bh * 131072;

  int qrowA = qg * 64 + l31;
  int qrowB = qrowA + 32;
  short8 qA0 = mk8(qgp + (size_t)qrowA * 32 + hi * 8);
  short8 qA1 = mk8(qgp + (size_t)qrowA * 32 + 16 + hi * 8);
  short8 qB0 = mk8(qgp + (size_t)qrowB * 32 + hi * 8);
  short8 qB1 = mk8(qgp + (size_t)qrowB * 32 + 16 + hi * 8);

  const f32x16 z16 = zero16();
  f32x16 oaccA = zero16();
  f32x16 oaccB = zero16();
  float lsumA = 0.f, lsumB = 0.f;

  // lane-linear fragment streams; tile stride = 1024 halves (2KB)
  const unsigned short* kpA = kt + (size_t)(jq * 32) * 1024 + lane * 8;
  const unsigned short* vpA = vt + (size_t)(jq * 32) * 1024 + lane * 8;
  const unsigned short* kpB = kpA + 1024;
  const unsigned short* vpB = vpA + 1024;

  short8 kA0 = mk8(kpA), kA1 = mk8(kpA + 512);
  short8 vA0 = mk8(vpA), vA1 = mk8(vpA + 512);
  short8 kB0 = mk8(kpB), kB1 = mk8(kpB + 512);
  short8 vB0 = mk8(vpB), vB1 = mk8(vpB + 512);
  kpA += 2048; vpA += 2048;                 // next A tile = t+2
  kpB += 2048; vpB += 2048;                 // next B tile = t+3

  for (int it = 0; it < 16; ++it) {          // 16 iters x 2 tiles x 32 j
    attn_sub(kA0, kA1, vA0, vA1, qA0, qA1, z16, lsumA, oaccA);
    attn_sub(kA0, kA1, vA0, vA1, qB0, qB1, z16, lsumB, oaccB);
    kA0 = mk8(kpA);                          // reload A with tile 2it+2
    kA1 = mk8(kpA + 512);                    // (last iter: dead prefetch, mapped ws)
    vA0 = mk8(vpA);
    vA1 = mk8(vpA + 512);
    kpA += 2048; vpA += 2048;

    attn_sub(kB0, kB1, vB0, vB1, qA0, qA1, z16, lsumA, oaccA);
    attn_sub(kB0, kB1, vB0, vB1, qB0, qB1, z16, lsumB, oaccB);
    kB0 = mk8(kpB);                          // reload B with tile 2it+3
    kB1 = mk8(kpB + 512);
    vB0 = mk8(vpB);
    vB1 = mk8(vpB + 512);
    kpB += 2048; vpB += 2048;
  }

  lsumA = redsum32(lsumA);   // pair row-totals for this j-quarter
  lsumB = redsum32(lsumB);

  if (jq > 0) {
#pragma unroll
    for (int i = 0; i < 16; ++i) {
      Ol[jq - 1][0][i][lane] = oaccA[i];
      Ol[jq - 1][1][i][lane] = oaccB[i];
    }
    Ll[jq - 1][0][lane] = lsumA;
    Ll[jq - 1][1][lane] = lsumB;
  }
  __syncthreads();
  if (jq == 0) {
    int b = bh >> 2, h = bh & 3;
#pragma unroll
    for (int qs = 0; qs < 2; ++qs) {
      float lsum = qs ? lsumB : lsumA;
      const f32x16& oacc = qs ? oaccB : oaccA;
      float rinv = 1.0f / (lsum + Ll[0][qs][lane] + Ll[1][qs][lane] + Ll[2][qs][lane]);
      int qrow = qs ? qrowB : qrowA;
      unsigned short* ob = attno + ((size_t)b * 4096 + qrow) * 128 + h * 32;
#pragma unroll
      for (int r2 = 0; r2 < 8; ++r2) {
        int reg = r2 * 2;
        int dv = (reg & 3) + 8 * (reg >> 2) + 4 * hi;
        float v0 = (oacc[reg] + Ol[0][qs][reg][lane] + Ol[1][qs][reg][lane] + Ol[2][qs][reg][lane]) * rinv;
        float v1 = (oacc[reg + 1] + Ol[0][qs][reg + 1][lane] + Ol[1][qs][reg + 1][lane] + Ol[2][qs][reg + 1][lane]) * rinv;
        *(unsigned int*)(ob + dv) = pk2(v0, v1);
      }
    }
  }
}

// ---------------- kernel 3: output projection + bias (1024 blocks) ----------------
__global__ __launch_bounds__(256) void k_out(const unsigned short* __restrict__ attno,
                                             const unsigned short* __restrict__ wo_bf,
                                             const float* __restrict__ bo,
                                             float* __restrict__ out) {
  int bid = blockIdx.x;            // 1024 = 4b * 4cog * 64pt
  int b = bid >> 8;
  int rem = bid & 255;
  int cog = rem >> 6;
  int p0 = (rem & 63) * 64;
  int co0 = cog * 64;
  int t = threadIdx.x, lane = t & 63, w = t >> 6;
  int lr = lane & 15, lg = lane >> 4;

  f32x4 z = {0.f, 0.f, 0.f, 0.f};
  f32x4 acc[4];
#pragma unroll
  for (int j = 0; j < 4; ++j) acc[j] = z;

  for (int c0 = 0; c0 < 128; c0 += 32) {
    short8 afr = mk8(wo_bf + (size_t)(co0 + w * 16 + lr) * 128 + c0 + lg * 8);
#pragma unroll
    for (int pt16 = 0; pt16 < 4; ++pt16) {
      short8 bfr = mk8(attno + (size_t)(b * 4096 + p0 + pt16 * 16 + lr) * 128 + c0 + lg * 8);
      acc[pt16] = MFMA16(afr, bfr, acc[pt16]);
    }
  }

#pragma unroll
  for (int pt16 = 0; pt16 < 4; ++pt16) {
#pragma unroll
    for (int r = 0; r < 4; ++r) {
      int co = co0 + w * 16 + lg * 4 + r;
      int p = p0 + pt16 * 16 + lr;
      out[((size_t)b * 256 + co) * 4096 + p] = acc[pt16][r] + bo[co];
    }
  }
}

extern "C" void kernel_launch(void* const* d_in, const int* in_sizes, int n_in,
                              void* d_out, int out_size, void* d_ws, size_t ws_size,
                              hipStream_t stream) {
  const float* x = (const float*)d_in[0];
  const float* g = (const float*)d_in[1];
  const float* wq = (const float*)d_in[2];
  const float* wo = (const float*)d_in[3];
  const float* bo = (const float*)d_in[4];
  float* out = (float*)d_out;

  char* ws = (char*)d_ws;
  unsigned short* wq_bf = (unsigned short*)(ws + 65536);     // 196608 B
  unsigned short* wo_bf = (unsigned short*)(ws + 262144);    // 65536 B
  unsigned short* qbuf = (unsigned short*)(ws + 327680);     // 4 MiB
  unsigned short* kbuf = (unsigned short*)(ws + 4521984);    // 4 MiB
  unsigned short* vbuf = (unsigned short*)(ws + 8716288);    // 4 MiB
  unsigned short* attno = (unsigned short*)(ws + 12910592);  // 4 MiB

  k_prep<<<dim3(384), dim3(256), 0, stream>>>(wq, wo, wq_bf, wo_bf);
  k_qkv<<<dim3(768), dim3(256), 0, stream>>>(x, g, wq_bf, qbuf, kbuf, vbuf);
  k_attn<<<dim3(1024), dim3(256), 0, stream>>>(qbuf, kbuf, vbuf, attno);
  k_out<<<dim3(1024), dim3(256), 0, stream>>>(attno, wo_bf, bo, out);
}

// Round 17
// 93.338 us; speedup vs baseline: 1.2831x; 1.2831x over previous
//
#include <hip/hip_runtime.h>
#include <hip/hip_bf16.h>
#include <stdint.h>
#include <stddef.h>

typedef __attribute__((ext_vector_type(8))) short short8;
typedef __attribute__((ext_vector_type(4))) float f32x4;
typedef __attribute__((ext_vector_type(16))) float f32x16;
typedef __attribute__((ext_vector_type(4))) unsigned int uint4v;

#define MFMA16(a, b, c) __builtin_amdgcn_mfma_f32_16x16x32_bf16((a), (b), (c), 0, 0, 0)
#define MFMA32(a, b, c) __builtin_amdgcn_mfma_f32_32x32x16_bf16((a), (b), (c), 0, 0, 0)

__device__ __forceinline__ unsigned short f2bf(float f) {
  unsigned int u = __builtin_bit_cast(unsigned int, f);
  u += 0x7fffu + ((u >> 16) & 1u);
  return (unsigned short)(u >> 16);
}

// validated integer RNE pack — cold paths
__device__ __forceinline__ unsigned int pk2(float lo, float hi) {
  return (unsigned int)f2bf(lo) | ((unsigned int)f2bf(hi) << 16);
}

// hot-path pack: official intrinsic -> compiler-emitted v_cvt_pk_bf16_f32
__device__ __forceinline__ unsigned int pkc(float lo, float hi) {
  __hip_bfloat162 h = __float22bfloat162_rn(make_float2(lo, hi));
  unsigned int u;
  __builtin_memcpy(&u, &h, 4);
  return u;
}

__device__ __forceinline__ short8 mk8(const unsigned short* p) {
  return *(const short8*)p;
}

__device__ __forceinline__ float redsum32(float v) {
  return v + __shfl_xor(v, 32);
}

__device__ __forceinline__ f32x16 zero16() {
  f32x16 v;
#pragma unroll
  for (int i = 0; i < 16; ++i) v[i] = 0.f;
  return v;
}

// swizzled offset into a [rows][40]-half LDS tile holding 32 data cols.
__device__ __forceinline__ int swz40(int row, int c) {
  return row * 40 + ((((c >> 3) ^ (row >> 3)) & 3) << 3) + (c & 7);
}

// ---------------- kernel 0: cast weights to bf16 ----------------
__global__ __launch_bounds__(256) void k_prep(const float* __restrict__ wq,
                                              const float* __restrict__ wo,
                                              unsigned short* __restrict__ wq_bf,
                                              unsigned short* __restrict__ wo_bf) {
  int i = blockIdx.x * 256 + threadIdx.x;
  if (i < 98304) wq_bf[i] = f2bf(wq[i]);
  if (i < 32768) wo_bf[i] = f2bf(wo[i]);
}

// ---------------- kernel 1: fused RMSNorm + QKV GEMM (r15, unchanged) ----------------
__global__ __launch_bounds__(256) void k_qkv(const float* __restrict__ x,
                                             const float* __restrict__ g,
                                             const unsigned short* __restrict__ wq_bf,
                                             unsigned short* __restrict__ qbuf,
                                             unsigned short* __restrict__ kbuf,
                                             unsigned short* __restrict__ vbuf) {
  int bid = blockIdx.x;            // 768 = 4b * 6ot * 32pt
  int b = bid / 192;
  int rem = bid % 192;
  int ot = rem / 32;
  int pt = rem % 32;
  int o0 = ot * 64, p0 = pt * 128;

  __shared__ unsigned short xnT[2][128 * 40];
  __shared__ float sqv[8][128];
  __shared__ float rl[128];

  int t = threadIdx.x;
  int lane = t & 63, w = t >> 6;
  int lr = lane & 15, lg = lane >> 4;
  int pq = t & 31;                 // p-quad: p = p0 + pq*4 + k
  int cp = t >> 5;                 // c-pair group 0..7

  const float* xb = x + (size_t)b * 256 * 4096;
  const unsigned short* wqrow = wq_bf + (size_t)(o0 + w * 16 + lr) * 256;

  f32x4 acc[8];
  f32x4 z = {0.f, 0.f, 0.f, 0.f};
#pragma unroll
  for (int i = 0; i < 8; ++i) acc[i] = z;
  f32x4 sacc = z;

#define STAGE_CHUNK(buf, c0)                                                   \
  {                                                                            \
    _Pragma("unroll")                                                          \
    for (int s = 0; s < 2; ++s) {                                              \
      int cb = (c0) + s * 16 + cp * 2;                                         \
      f32x4 xa = *(const f32x4*)&xb[(size_t)cb * 4096 + p0 + pq * 4];          \
      f32x4 xc = *(const f32x4*)&xb[(size_t)(cb + 1) * 4096 + p0 + pq * 4];    \
      float ga = g[cb], gc = g[cb + 1];                                        \
      int cloc = s * 16 + cp * 2;                                              \
      _Pragma("unroll")                                                        \
      for (int k = 0; k < 4; ++k) {                                            \
        sacc[k] += xa[k] * xa[k] + xc[k] * xc[k];                              \
        *(unsigned int*)&xnT[buf][swz40(pq * 4 + k, cloc)] =                   \
            pkc(xa[k] * ga, xc[k] * gc);                                       \
      }                                                                        \
    }                                                                          \
  }

  STAGE_CHUNK(0, 0)
  __syncthreads();

  for (int cc = 0; cc < 8; ++cc) {
    int cur = cc & 1;
    if (cc < 7) STAGE_CHUNK(cur ^ 1, (cc + 1) * 32)
    short8 af = mk8(wqrow + cc * 32 + lg * 8);
#pragma unroll
    for (int pt16 = 0; pt16 < 8; ++pt16) {
      short8 bf = mk8(&xnT[cur][swz40(pt16 * 16 + lr, lg * 8)]);
      acc[pt16] = MFMA16(af, bf, acc[pt16]);
    }
    __syncthreads();
  }
#undef STAGE_CHUNK

#pragma unroll
  for (int k = 0; k < 4; ++k) sqv[cp][pq * 4 + k] = sacc[k];
  __syncthreads();
  if (t < 128) {
    float tot = 0.f;
#pragma unroll
    for (int r = 0; r < 8; ++r) tot += sqv[r][t];
    rl[t] = rsqrtf(tot * (1.0f / 256.0f) + 1e-12f);
  }
  __syncthreads();

  const float cexp = 0.25505654427102996f;   // 32^-0.5 * log2(e), folded into K
  int obase = o0 + w * 16 + lg * 4;          // multiple of 4
  if (obase < 128) {
    int h = obase >> 5, d0 = obase & 31;
    unsigned short* dst = qbuf + ((size_t)(b * 4 + h) * 4096) * 32;
#pragma unroll
    for (int pt16 = 0; pt16 < 8; ++pt16) {
      int p = p0 + pt16 * 16 + lr;
      float rr = rl[pt16 * 16 + lr];
      unsigned int u0 = pk2(acc[pt16][0] * rr, acc[pt16][1] * rr);
      unsigned int u1 = pk2(acc[pt16][2] * rr, acc[pt16][3] * rr);
      uint2 uu = {u0, u1};
      *(uint2*)(dst + (size_t)p * 32 + d0) = uu;
    }
  } else if (obase < 256) {
    int oh = obase - 128;
    int h = oh >> 5, d0 = oh & 31;
    int frag = d0 >> 4, hi = (d0 >> 3) & 1, i0 = d0 & 7;
    unsigned short* dst = kbuf + (size_t)(b * 4 + h) * 131072
                         + frag * 512 + hi * 256 + i0;
#pragma unroll
    for (int pt16 = 0; pt16 < 8; ++pt16) {
      int jj = p0 + pt16 * 16 + lr;
      float rr = rl[pt16 * 16 + lr] * cexp;
      int jtile = jj >> 5, j31 = jj & 31;
      uint2 uu = {pk2(acc[pt16][0] * rr, acc[pt16][1] * rr),
                  pk2(acc[pt16][2] * rr, acc[pt16][3] * rr)};
      *(uint2*)(dst + (size_t)jtile * 1024 + j31 * 8) = uu;
    }
  } else {
    int oh = obase - 256;
    int h = oh >> 5, d0 = oh & 31;
    unsigned short* dst = vbuf + (size_t)(b * 4 + h) * 131072;
    int sl = (lr & 3) | ((lr & 4) << 1) | ((lr & 8) >> 1);
#pragma unroll
    for (int pt16 = 0; pt16 < 8; ++pt16) {
      int jj = p0 + pt16 * 16 + sl;
      float rr = rl[pt16 * 16 + lr];
      int jtile = jj >> 5, j5 = jj & 31;
      int frag = j5 >> 4, hi = (j5 >> 3) & 1, i = j5 & 7;
      size_t base = (size_t)jtile * 1024 + frag * 512 + hi * 256 + i;
#pragma unroll
      for (int r = 0; r < 4; ++r)
        dst[base + (d0 + r) * 8] = f2bf(acc[pt16][r] * rr);
    }
  }
}

// ---------------- kernel 2: flash attention, 2 q-subgroups per wave ----------------
// grid 1024 = 16 bh x 64 q-groups of 64 rows; 4 waves = 4 j-quarters.
// Each wave reuses every K/V fragment for TWO 32-row q-subgroups -> L1 bytes/FLOP
// halved. __launch_bounds__(256,3): 168-reg cap — r16's (256,4)=128 spilled
// (~130 live regs) causing 130MB/dispatch scratch traffic.
__device__ __forceinline__ void attn_sub(short8 kf0, short8 kf1, short8 vf0, short8 vf1,
                                         short8 qf0, short8 qf1,
                                         const f32x16& z16, float& lsum, f32x16& oacc) {
  f32x16 s = MFMA32(kf0, qf0, z16);
  s = MFMA32(kf1, qf1, s);

  float p[16];
#pragma unroll
  for (int i = 0; i < 16; ++i) p[i] = __builtin_amdgcn_exp2f(s[i]);

  float s0 = ((p[0] + p[1]) + (p[2] + p[3])) + ((p[4] + p[5]) + (p[6] + p[7]));
  float s1 = ((p[8] + p[9]) + (p[10] + p[11])) + ((p[12] + p[13]) + (p[14] + p[15]));
  lsum += s0 + s1;

  uint4v u0 = {pkc(p[0], p[1]), pkc(p[2], p[3]), pkc(p[4], p[5]), pkc(p[6], p[7])};
  uint4v u1 = {pkc(p[8], p[9]), pkc(p[10], p[11]), pkc(p[12], p[13]), pkc(p[14], p[15])};
  short8 pf0 = __builtin_bit_cast(short8, u0);
  short8 pf1 = __builtin_bit_cast(short8, u1);

  oacc = MFMA32(vf0, pf0, oacc);
  oacc = MFMA32(vf1, pf1, oacc);
}

__global__ __launch_bounds__(256, 3) void k_attn(const unsigned short* __restrict__ qbuf,
                                                 const unsigned short* __restrict__ kbuf,
                                                 const unsigned short* __restrict__ vbuf,
                                                 unsigned short* __restrict__ attno) {
  __shared__ float Ol[3][2][16][64];   // partner O partials (jq 1..3, 2 subgroups)
  __shared__ float Ll[3][2][64];       // partner lsum

  int bid = blockIdx.x;
  int wid = ((bid & 7) << 7) | (bid >> 3);   // XCD-contiguous (1024 % 8 == 0)
  int qg = wid & 63, bh = wid >> 6;
  int t = threadIdx.x, lane = t & 63, jq = t >> 6;
  int l31 = lane & 31, hi = lane >> 5;

  const unsigned short* qgp = qbuf + (size_t)bh * 4096 * 32;
  const unsigned short* kt = kbuf + (size_t)bh * 131072;
  const unsigned short* vt = vbuf + (size_t)bh * 131072;

  int qrowA = qg * 64 + l31;
  int qrowB = qrowA + 32;
  short8 qA0 = mk8(qgp + (size_t)qrowA * 32 + hi * 8);
  short8 qA1 = mk8(qgp + (size_t)qrowA * 32 + 16 + hi * 8);
  short8 qB0 = mk8(qgp + (size_t)qrowB * 32 + hi * 8);
  short8 qB1 = mk8(qgp + (size_t)qrowB * 32 + 16 + hi * 8);

  const f32x16 z16 = zero16();
  f32x16 oaccA = zero16();
  f32x16 oaccB = zero16();
  float lsumA = 0.f, lsumB = 0.f;

  // lane-linear fragment streams; tile stride = 1024 halves (2KB)
  const unsigned short* kpA = kt + (size_t)(jq * 32) * 1024 + lane * 8;
  const unsigned short* vpA = vt + (size_t)(jq * 32) * 1024 + lane * 8;
  const unsigned short* kpB = kpA + 1024;
  const unsigned short* vpB = vpA + 1024;

  short8 kA0 = mk8(kpA), kA1 = mk8(kpA + 512);
  short8 vA0 = mk8(vpA), vA1 = mk8(vpA + 512);
  short8 kB0 = mk8(kpB), kB1 = mk8(kpB + 512);
  short8 vB0 = mk8(vpB), vB1 = mk8(vpB + 512);
  kpA += 2048; vpA += 2048;                 // next A tile = t+2
  kpB += 2048; vpB += 2048;                 // next B tile = t+3

  for (int it = 0; it < 16; ++it) {          // 16 iters x 2 tiles x 32 j
    attn_sub(kA0, kA1, vA0, vA1, qA0, qA1, z16, lsumA, oaccA);
    attn_sub(kA0, kA1, vA0, vA1, qB0, qB1, z16, lsumB, oaccB);
    kA0 = mk8(kpA);                          // reload A with tile 2it+2
    kA1 = mk8(kpA + 512);                    // (last iter: dead prefetch, mapped ws)
    vA0 = mk8(vpA);
    vA1 = mk8(vpA + 512);
    kpA += 2048; vpA += 2048;

    attn_sub(kB0, kB1, vB0, vB1, qA0, qA1, z16, lsumA, oaccA);
    attn_sub(kB0, kB1, vB0, vB1, qB0, qB1, z16, lsumB, oaccB);
    kB0 = mk8(kpB);                          // reload B with tile 2it+3
    kB1 = mk8(kpB + 512);
    vB0 = mk8(vpB);
    vB1 = mk8(vpB + 512);
    kpB += 2048; vpB += 2048;
  }

  lsumA = redsum32(lsumA);   // pair row-totals for this j-quarter
  lsumB = redsum32(lsumB);

  if (jq > 0) {
#pragma unroll
    for (int i = 0; i < 16; ++i) {
      Ol[jq - 1][0][i][lane] = oaccA[i];
      Ol[jq - 1][1][i][lane] = oaccB[i];
    }
    Ll[jq - 1][0][lane] = lsumA;
    Ll[jq - 1][1][lane] = lsumB;
  }
  __syncthreads();
  if (jq == 0) {
    int b = bh >> 2, h = bh & 3;
#pragma unroll
    for (int qs = 0; qs < 2; ++qs) {
      float lsum = qs ? lsumB : lsumA;
      const f32x16& oacc = qs ? oaccB : oaccA;
      float rinv = 1.0f / (lsum + Ll[0][qs][lane] + Ll[1][qs][lane] + Ll[2][qs][lane]);
      int qrow = qs ? qrowB : qrowA;
      unsigned short* ob = attno + ((size_t)b * 4096 + qrow) * 128 + h * 32;
#pragma unroll
      for (int r2 = 0; r2 < 8; ++r2) {
        int reg = r2 * 2;
        int dv = (reg & 3) + 8 * (reg >> 2) + 4 * hi;
        float v0 = (oacc[reg] + Ol[0][qs][reg][lane] + Ol[1][qs][reg][lane] + Ol[2][qs][reg][lane]) * rinv;
        float v1 = (oacc[reg + 1] + Ol[0][qs][reg + 1][lane] + Ol[1][qs][reg + 1][lane] + Ol[2][qs][reg + 1][lane]) * rinv;
        *(unsigned int*)(ob + dv) = pk2(v0, v1);
      }
    }
  }
}

// ---------------- kernel 3: output projection + bias (1024 blocks) ----------------
__global__ __launch_bounds__(256) void k_out(const unsigned short* __restrict__ attno,
                                             const unsigned short* __restrict__ wo_bf,
                                             const float* __restrict__ bo,
                                             float* __restrict__ out) {
  int bid = blockIdx.x;            // 1024 = 4b * 4cog * 64pt
  int b = bid >> 8;
  int rem = bid & 255;
  int cog = rem >> 6;
  int p0 = (rem & 63) * 64;
  int co0 = cog * 64;
  int t = threadIdx.x, lane = t & 63, w = t >> 6;
  int lr = lane & 15, lg = lane >> 4;

  f32x4 z = {0.f, 0.f, 0.f, 0.f};
  f32x4 acc[4];
#pragma unroll
  for (int j = 0; j < 4; ++j) acc[j] = z;

  for (int c0 = 0; c0 < 128; c0 += 32) {
    short8 afr = mk8(wo_bf + (size_t)(co0 + w * 16 + lr) * 128 + c0 + lg * 8);
#pragma unroll
    for (int pt16 = 0; pt16 < 4; ++pt16) {
      short8 bfr = mk8(attno + (size_t)(b * 4096 + p0 + pt16 * 16 + lr) * 128 + c0 + lg * 8);
      acc[pt16] = MFMA16(afr, bfr, acc[pt16]);
    }
  }

#pragma unroll
  for (int pt16 = 0; pt16 < 4; ++pt16) {
#pragma unroll
    for (int r = 0; r < 4; ++r) {
      int co = co0 + w * 16 + lg * 4 + r;
      int p = p0 + pt16 * 16 + lr;
      out[((size_t)b * 256 + co) * 4096 + p] = acc[pt16][r] + bo[co];
    }
  }
}

extern "C" void kernel_launch(void* const* d_in, const int* in_sizes, int n_in,
                              void* d_out, int out_size, void* d_ws, size_t ws_size,
                              hipStream_t stream) {
  const float* x = (const float*)d_in[0];
  const float* g = (const float*)d_in[1];
  const float* wq = (const float*)d_in[2];
  const float* wo = (const float*)d_in[3];
  const float* bo = (const float*)d_in[4];
  float* out = (float*)d_out;

  char* ws = (char*)d_ws;
  unsigned short* wq_bf = (unsigned short*)(ws + 65536);     // 196608 B
  unsigned short* wo_bf = (unsigned short*)(ws + 262144);    // 65536 B
  unsigned short* qbuf = (unsigned short*)(ws + 327680);     // 4 MiB
  unsigned short* kbuf = (unsigned short*)(ws + 4521984);    // 4 MiB
  unsigned short* vbuf = (unsigned short*)(ws + 8716288);    // 4 MiB
  unsigned short* attno = (unsigned short*)(ws + 12910592);  // 4 MiB

  k_prep<<<dim3(384), dim3(256), 0, stream>>>(wq, wo, wq_bf, wo_bf);
  k_qkv<<<dim3(768), dim3(256), 0, stream>>>(x, g, wq_bf, qbuf, kbuf, vbuf);
  k_attn<<<dim3(1024), dim3(256), 0, stream>>>(qbuf, kbuf, vbuf, attno);
  k_out<<<dim3(1024), dim3(256), 0, stream>>>(attno, wo_bf, bo, out);
}